// Round 1
// baseline (287.261 us; speedup 1.0000x reference)
//
#include <hip/hip_runtime.h>
#include <hip/hip_bf16.h>
#include <cstdint>

// Problem constants
#define NTOK 8192
#define DIN  1024
#define DOUT 1024
#define NEXP 8

typedef __attribute__((ext_vector_type(8)))  __bf16 bf16x8;
typedef __attribute__((ext_vector_type(4)))  float  f32x4;

__device__ __forceinline__ unsigned short f2bf(float f) {
    unsigned int u = __builtin_bit_cast(unsigned int, f);
    u += 0x7FFFu + ((u >> 16) & 1u);   // round-to-nearest-even
    return (unsigned short)(u >> 16);
}

__device__ __forceinline__ void cp16(const void* gsrc, void* ldst) {
    __builtin_amdgcn_global_load_lds(
        (const __attribute__((address_space(1))) void*)gsrc,
        (__attribute__((address_space(3))) void*)ldst,
        16, 0, 0);
}

#define BAR() asm volatile("s_barrier" ::: "memory")

// ---------------------------------------------------------------------------
// Prep kernel (unchanged; non-GEMM time ~112us is harness-fixed — invariant
// across R1..R7's very different prep structures):
//   blocks [0, 2048):     We [e][k][o] fp32 -> WebT [e][o][k] bf16
//   blocks [2048, 2304):  gate softmax(x@Wg+bg) + x -> bf16
// ---------------------------------------------------------------------------
__global__ __launch_bounds__(256) void prep_kernel(
    const float* __restrict__ x, const float* __restrict__ We,
    const float* __restrict__ Wg, const float* __restrict__ bg,
    unsigned short* __restrict__ xb, unsigned short* __restrict__ wt,
    float* __restrict__ g)
{
    __shared__ float smem[12416];

    int t = threadIdx.x;

    if (blockIdx.x < 2048) {
        unsigned short* tile = (unsigned short*)smem;   // [64][72]
        int b = blockIdx.x;
        int e  = b >> 8;
        int kt = (b >> 4) & 15;
        int ot = b & 15;

        const float* src = We + ((size_t)e << 20) + (size_t)(kt * 64) * DOUT + ot * 64;
        unsigned short* dst = wt + ((size_t)e << 20) + (size_t)(ot * 64) * DIN + kt * 64;

        int kl = t >> 2;
        int og = (t & 3) * 16;
#pragma unroll
        for (int c = 0; c < 4; ++c) {
            int o = og + c * 4;
            float4 v = *(const float4*)&src[(size_t)kl * DOUT + o];
            ushort4 u;
            u.x = f2bf(v.x); u.y = f2bf(v.y); u.z = f2bf(v.z); u.w = f2bf(v.w);
            *(ushort4*)&tile[kl * 72 + o] = u;
        }
        __syncthreads();
        int ol = t >> 2;
        int kg = (t & 3) * 16;
        unsigned short tmp[16];
#pragma unroll
        for (int i = 0; i < 16; ++i) tmp[i] = tile[(kg + i) * 72 + ol];
        *(uint4*)&dst[(size_t)ol * DIN + kg]     = *(uint4*)&tmp[0];
        *(uint4*)&dst[(size_t)ol * DIN + kg + 8] = *(uint4*)&tmp[8];
    } else {
        float* WgL = smem;          // [8][1024] transposed Wg
        float* xL  = smem + 8192;   // [32][132] x chunk
        int n0 = (blockIdx.x - 2048) * 32;

#pragma unroll
        for (int q = 0; q < 8; ++q) {
            int fidx = q * 256 + t;
            int k  = fidx >> 1;
            int eh = (fidx & 1) * 4;
            float4 v = *(const float4*)&Wg[(size_t)k * 8 + eh];
            WgL[(eh + 0) * 1024 + k] = v.x;
            WgL[(eh + 1) * 1024 + k] = v.y;
            WgL[(eh + 2) * 1024 + k] = v.z;
            WgL[(eh + 3) * 1024 + k] = v.w;
        }

        int tt = t & 31;
        int e  = t >> 5;
        float acc = 0.f;

        for (int c = 0; c < 8; ++c) {
            int kb = c * 128;
#pragma unroll
            for (int q = 0; q < 4; ++q) {
                int fidx = q * 256 + t;
                int row = fidx >> 5;
                int kk  = (fidx & 31) * 4;
                float4 v = *(const float4*)&x[(size_t)(n0 + row) * DIN + kb + kk];
                ushort4 u;
                u.x = f2bf(v.x); u.y = f2bf(v.y); u.z = f2bf(v.z); u.w = f2bf(v.w);
                *(ushort4*)&xb[(size_t)(n0 + row) * DIN + kb + kk] = u;
                *(float4*)&xL[row * 132 + kk] = v;
            }
            __syncthreads();
#pragma unroll
            for (int kk = 0; kk < 128; kk += 4) {
                float4 xv = *(const float4*)&xL[tt * 132 + kk];
                float4 wv = *(const float4*)&WgL[e * 1024 + kb + kk];
                acc += xv.x * wv.x + xv.y * wv.y + xv.z * wv.z + xv.w * wv.w;
            }
            __syncthreads();
        }

        float* lg = xL;
        lg[tt * 8 + e] = acc + bg[e];
        __syncthreads();
        if (t < 32) {
            float l[8];
#pragma unroll
            for (int i = 0; i < 8; ++i) l[i] = lg[t * 8 + i];
            float m = l[0];
#pragma unroll
            for (int i = 1; i < 8; ++i) m = fmaxf(m, l[i]);
            float s = 0.f;
#pragma unroll
            for (int i = 0; i < 8; ++i) { l[i] = __expf(l[i] - m); s += l[i]; }
            float inv = 1.0f / s;
            float4 p0 = make_float4(l[0]*inv, l[1]*inv, l[2]*inv, l[3]*inv);
            float4 p1 = make_float4(l[4]*inv, l[5]*inv, l[6]*inv, l[7]*inv);
            *(float4*)&g[(size_t)(n0 + tt) * 8]     = p0;
            *(float4*)&g[(size_t)(n0 + tt) * 8 + 4] = p1;
        }
    }
}

// ---------------------------------------------------------------------------
// Main MoE GEMM — T3/T4/T5 restructure (counted-vmcnt pipeline):
//  - BM=256 x BN=128, BK=64, 8 waves (4M x 2N), grid 256 = 1 block/CU
//  - triple-buffered LDS (3 x 48KB = 144KB), tiles staged 2 ahead
//  - raw s_barrier (NO vmcnt drain) + counted s_waitcnt vmcnt(10/6/0):
//    in steady state 10 loads stay in flight across every barrier
//  - 2 MFMA phases/K-tile, s_setprio(1) around each 16-MFMA cluster
//  - LDS byte layout = R2/R7's measured conflict-free scheme (128B-stride
//    rows, chunk XOR row&7 swizzle; inverse-swz global src, linear dest)
//  - K-chain is continuous across the 8 experts (128 K-tiles); per-expert
//    gate/bias merge is register-only + L1-hot g/be loads. Any compiler
//    vmcnt over-drain at merges is a small tax, never a race (the loads
//    the counted waits require retired are always the oldest in FIFO).
// ---------------------------------------------------------------------------
__global__ __launch_bounds__(512, 2) void moe_gemm_kernel(
    const unsigned short* __restrict__ xb,   // [NTOK][DIN] bf16
    const unsigned short* __restrict__ wt,   // [E][DOUT][DIN] bf16
    const float* __restrict__ g,             // [NTOK][E]
    const float* __restrict__ be,            // [E][DOUT]
    float* __restrict__ out)                 // [NTOK][DOUT]
{
    __shared__ unsigned short lA[3][256 * 64];   // 3 x 32 KB
    __shared__ unsigned short lB[3][128 * 64];   // 3 x 16 KB

    int bid = blockIdx.x;
    // XCD-chunked swizzle: XCD x gets bm in [4x, 4x+4), all bn -> A-slab L2 reuse
    int wg = ((bid & 7) << 5) | (bid >> 3);
    int bm = wg >> 3;          // 0..31
    int bn = wg & 7;           // 0..7

    int tid  = threadIdx.x;    // 0..511
    int lane = tid & 63;
    int wave = tid >> 6;       // 0..7
    int wm = wave >> 1;        // 0..3  (64-row slab within 256)
    int wn = wave & 1;         // 0..1  (64-col slab within 128)

    int rA   = lane & 15;
    int quad = lane >> 4;
    int swz  = rA & 7;
    int kp0  = ((quad    ) ^ swz) << 3;   // elem offset of logical chunk quad,   k-half 0
    int kp1  = ((quad + 4) ^ swz) << 3;   // elem offset of logical chunk quad+4, k-half 1
    int aRowB = (wm * 64 + rA) * 64;      // + i*1024 + kp
    int bRowB = (wn * 64 + rA) * 64;      // + j*1024 + kp

    // staging geometry (identical byte layout to R2's verified pattern):
    // thread covers (row r*64 + tid>>3, physical chunk tid&7);
    // physical chunk holds logical chunk (tid&7) ^ (row&7)
    int srcOff = (tid >> 3) * DIN + (((tid & 7) ^ ((tid >> 3) & 7)) << 3);
    int wOff   = wave * 512;              // wave-uniform LDS base (elems); HW adds lane*16B

    const unsigned short* aB = xb + (size_t)(bm * 256) * DIN;
    const unsigned short* bB = wt + (size_t)(bn * 128) * DIN;   // + (e<<20)

    // ---- prologue: stage tiles 0 (buf0) and 1 (buf1); 12 loads in flight ----
#pragma unroll
    for (int r = 0; r < 4; ++r)
        cp16(aB + (size_t)(r * 64) * DIN + srcOff, &lA[0][r * 4096 + wOff]);
#pragma unroll
    for (int r = 0; r < 2; ++r)
        cp16(bB + (size_t)(r * 64) * DIN + srcOff, &lB[0][r * 4096 + wOff]);
#pragma unroll
    for (int r = 0; r < 4; ++r)
        cp16(aB + (size_t)(r * 64) * DIN + 64 + srcOff, &lA[1][r * 4096 + wOff]);
#pragma unroll
    for (int r = 0; r < 2; ++r)
        cp16(bB + (size_t)(r * 64) * DIN + 64 + srcOff, &lB[1][r * 4096 + wOff]);

    f32x4 outAcc[4][4] = {};
    f32x4 acc[4][4] = {};
    const f32x4 fz = {0.f, 0.f, 0.f, 0.f};

    int cur = 0;

#pragma unroll 1
    for (int e = 0; e < NEXP; ++e) {
#pragma unroll 1
        for (int kt = 0; kt < 16; ++kt) {
            int t = (e << 4) + kt;
            int nxt = cur ? (cur - 1) : 2;   // (t+2) % 3

            // ---- stage A of tile t+2, then counted wait for tile t ----
            if (t < 126) {
                int tt = t + 2;
                const unsigned short* a2 = aB + ((tt & 15) << 6);
#pragma unroll
                for (int r = 0; r < 4; ++r)
                    cp16(a2 + (size_t)(r * 64) * DIN + srcOff, &lA[nxt][r * 4096 + wOff]);
                // newest 10 = {A(t+2):4, tile(t+1):6}; waits tile t's 6 retired
                asm volatile("s_waitcnt vmcnt(10)" ::: "memory");
            } else if (t == 126) {
                asm volatile("s_waitcnt vmcnt(6)" ::: "memory");
            } else {
                asm volatile("s_waitcnt vmcnt(0)" ::: "memory");
            }
            BAR();   // all waves: buf[cur] fully staged

            // ---- phase A: read all B frags + A frags i=0,1; stage B(t+2); MFMA ----
            bf16x8 bfr[4][2], afA[2][2];
#pragma unroll
            for (int j = 0; j < 4; ++j) {
                bfr[j][0] = *(const bf16x8*)&lB[cur][bRowB + j * 1024 + kp0];
                bfr[j][1] = *(const bf16x8*)&lB[cur][bRowB + j * 1024 + kp1];
            }
#pragma unroll
            for (int i = 0; i < 2; ++i) {
                afA[i][0] = *(const bf16x8*)&lA[cur][aRowB + i * 1024 + kp0];
                afA[i][1] = *(const bf16x8*)&lA[cur][aRowB + i * 1024 + kp1];
            }
            if (t < 126) {
                int tt = t + 2;
                const unsigned short* b2 = wt + ((size_t)(tt >> 4) << 20)
                                         + (size_t)(bn * 128) * DIN + ((tt & 15) << 6);
#pragma unroll
                for (int r = 0; r < 2; ++r)
                    cp16(b2 + (size_t)(r * 64) * DIN + srcOff, &lB[nxt][r * 4096 + wOff]);
            }
            __builtin_amdgcn_s_setprio(1);
#pragma unroll
            for (int i = 0; i < 2; ++i)
#pragma unroll
                for (int j = 0; j < 4; ++j) {
                    acc[i][j] = __builtin_amdgcn_mfma_f32_16x16x32_bf16(
                        afA[i][0], bfr[j][0], acc[i][j], 0, 0, 0);
                    acc[i][j] = __builtin_amdgcn_mfma_f32_16x16x32_bf16(
                        afA[i][1], bfr[j][1], acc[i][j], 0, 0, 0);
                }
            __builtin_amdgcn_s_setprio(0);
            BAR();   // phase lockstep

            // ---- phase B: read A frags i=2,3; MFMA (B frags still live) ----
            bf16x8 afB[2][2];
#pragma unroll
            for (int i = 0; i < 2; ++i) {
                afB[i][0] = *(const bf16x8*)&lA[cur][aRowB + (i + 2) * 1024 + kp0];
                afB[i][1] = *(const bf16x8*)&lA[cur][aRowB + (i + 2) * 1024 + kp1];
            }
            __builtin_amdgcn_s_setprio(1);
#pragma unroll
            for (int i = 0; i < 2; ++i)
#pragma unroll
                for (int j = 0; j < 4; ++j) {
                    acc[i + 2][j] = __builtin_amdgcn_mfma_f32_16x16x32_bf16(
                        afB[i][0], bfr[j][0], acc[i + 2][j], 0, 0, 0);
                    acc[i + 2][j] = __builtin_amdgcn_mfma_f32_16x16x32_bf16(
                        afB[i][1], bfr[j][1], acc[i + 2][j], 0, 0, 0);
                }
            __builtin_amdgcn_s_setprio(0);
            BAR();   // all waves done reading buf[cur]; restaged at t+1

            cur = (cur == 2) ? 0 : cur + 1;
        }

        // ---- merge expert e: outAcc += g[row,e] * (acc + be[e,col]); reset acc ----
        float bv[4];
#pragma unroll
        for (int j = 0; j < 4; ++j)
            bv[j] = be[(size_t)e * DOUT + bn * 128 + wn * 64 + j * 16 + rA];
#pragma unroll
        for (int i = 0; i < 4; ++i) {
            int rbase = bm * 256 + wm * 64 + i * 16 + quad * 4;
            float g0 = g[(size_t)(rbase + 0) * 8 + e];
            float g1 = g[(size_t)(rbase + 1) * 8 + e];
            float g2 = g[(size_t)(rbase + 2) * 8 + e];
            float g3 = g[(size_t)(rbase + 3) * 8 + e];
#pragma unroll
            for (int j = 0; j < 4; ++j) {
                outAcc[i][j].x += g0 * (acc[i][j].x + bv[j]);
                outAcc[i][j].y += g1 * (acc[i][j].y + bv[j]);
                outAcc[i][j].z += g2 * (acc[i][j].z + bv[j]);
                outAcc[i][j].w += g3 * (acc[i][j].w + bv[j]);
                acc[i][j] = fz;
            }
        }
    }

    // ---- epilogue: C layout col = lane&15, row = quad*4 + reg ----
#pragma unroll
    for (int i = 0; i < 4; ++i) {
        int rowb = bm * 256 + wm * 64 + i * 16 + quad * 4;
#pragma unroll
        for (int j = 0; j < 4; ++j) {
            int col = bn * 128 + wn * 64 + j * 16 + rA;
            out[(size_t)(rowb + 0) * DOUT + col] = outAcc[i][j].x;
            out[(size_t)(rowb + 1) * DOUT + col] = outAcc[i][j].y;
            out[(size_t)(rowb + 2) * DOUT + col] = outAcc[i][j].z;
            out[(size_t)(rowb + 3) * DOUT + col] = outAcc[i][j].w;
        }
    }
}

// ---------------------------------------------------------------------------
extern "C" void kernel_launch(void* const* d_in, const int* in_sizes, int n_in,
                              void* d_out, int out_size, void* d_ws, size_t ws_size,
                              hipStream_t stream)
{
    const float* x  = (const float*)d_in[0];   // [8192,1024]
    const float* We = (const float*)d_in[1];   // [8,1024,1024]
    const float* be = (const float*)d_in[2];   // [8,1024]
    const float* Wg = (const float*)d_in[3];   // [1024,8]
    const float* bg = (const float*)d_in[4];   // [8]
    float* out = (float*)d_out;                // [8192,1024]

    // workspace: xb (16.78MB bf16) | WebT (16.78MB bf16) | g (256KB f32)
    unsigned short* xb = (unsigned short*)d_ws;
    unsigned short* wt = xb + (size_t)NTOK * DIN;
    float* g = (float*)(wt + (size_t)NEXP * DOUT * DIN);

    prep_kernel<<<2048 + 256, 256, 0, stream>>>(x, We, Wg, bg, xb, wt, g);
    moe_gemm_kernel<<<(NTOK / 256) * (DOUT / 128), 512, 0, stream>>>(xb, wt, g, be, out);
}

// Round 2
// 267.124 us; speedup vs baseline: 1.0754x; 1.0754x over previous
//
#include <hip/hip_runtime.h>
#include <hip/hip_bf16.h>
#include <cstdint>

// Problem constants
#define NTOK 8192
#define DIN  1024
#define DOUT 1024
#define NEXP 8

typedef __attribute__((ext_vector_type(8)))  __bf16 bf16x8;
typedef __attribute__((ext_vector_type(4)))  float  f32x4;

__device__ __forceinline__ unsigned short f2bf(float f) {
    unsigned int u = __builtin_bit_cast(unsigned int, f);
    u += 0x7FFFu + ((u >> 16) & 1u);   // round-to-nearest-even
    return (unsigned short)(u >> 16);
}

__device__ __forceinline__ void cp16(const void* gsrc, void* ldst) {
    __builtin_amdgcn_global_load_lds(
        (const __attribute__((address_space(1))) void*)gsrc,
        (__attribute__((address_space(3))) void*)ldst,
        16, 0, 0);
}

#define BAR() asm volatile("s_barrier" ::: "memory")

// ---------------------------------------------------------------------------
// Prep kernel (unchanged):
//   blocks [0, 2048):     We [e][k][o] fp32 -> WebT [e][o][k] bf16
//   blocks [2048, 2304):  gate softmax(x@Wg+bg) + x -> bf16
// ---------------------------------------------------------------------------
__global__ __launch_bounds__(256) void prep_kernel(
    const float* __restrict__ x, const float* __restrict__ We,
    const float* __restrict__ Wg, const float* __restrict__ bg,
    unsigned short* __restrict__ xb, unsigned short* __restrict__ wt,
    float* __restrict__ g)
{
    __shared__ float smem[12416];

    int t = threadIdx.x;

    if (blockIdx.x < 2048) {
        unsigned short* tile = (unsigned short*)smem;   // [64][72]
        int b = blockIdx.x;
        int e  = b >> 8;
        int kt = (b >> 4) & 15;
        int ot = b & 15;

        const float* src = We + ((size_t)e << 20) + (size_t)(kt * 64) * DOUT + ot * 64;
        unsigned short* dst = wt + ((size_t)e << 20) + (size_t)(ot * 64) * DIN + kt * 64;

        int kl = t >> 2;
        int og = (t & 3) * 16;
#pragma unroll
        for (int c = 0; c < 4; ++c) {
            int o = og + c * 4;
            float4 v = *(const float4*)&src[(size_t)kl * DOUT + o];
            ushort4 u;
            u.x = f2bf(v.x); u.y = f2bf(v.y); u.z = f2bf(v.z); u.w = f2bf(v.w);
            *(ushort4*)&tile[kl * 72 + o] = u;
        }
        __syncthreads();
        int ol = t >> 2;
        int kg = (t & 3) * 16;
        unsigned short tmp[16];
#pragma unroll
        for (int i = 0; i < 16; ++i) tmp[i] = tile[(kg + i) * 72 + ol];
        *(uint4*)&dst[(size_t)ol * DIN + kg]     = *(uint4*)&tmp[0];
        *(uint4*)&dst[(size_t)ol * DIN + kg + 8] = *(uint4*)&tmp[8];
    } else {
        float* WgL = smem;          // [8][1024] transposed Wg
        float* xL  = smem + 8192;   // [32][132] x chunk
        int n0 = (blockIdx.x - 2048) * 32;

#pragma unroll
        for (int q = 0; q < 8; ++q) {
            int fidx = q * 256 + t;
            int k  = fidx >> 1;
            int eh = (fidx & 1) * 4;
            float4 v = *(const float4*)&Wg[(size_t)k * 8 + eh];
            WgL[(eh + 0) * 1024 + k] = v.x;
            WgL[(eh + 1) * 1024 + k] = v.y;
            WgL[(eh + 2) * 1024 + k] = v.z;
            WgL[(eh + 3) * 1024 + k] = v.w;
        }

        int tt = t & 31;
        int e  = t >> 5;
        float acc = 0.f;

        for (int c = 0; c < 8; ++c) {
            int kb = c * 128;
#pragma unroll
            for (int q = 0; q < 4; ++q) {
                int fidx = q * 256 + t;
                int row = fidx >> 5;
                int kk  = (fidx & 31) * 4;
                float4 v = *(const float4*)&x[(size_t)(n0 + row) * DIN + kb + kk];
                ushort4 u;
                u.x = f2bf(v.x); u.y = f2bf(v.y); u.z = f2bf(v.z); u.w = f2bf(v.w);
                *(ushort4*)&xb[(size_t)(n0 + row) * DIN + kb + kk] = u;
                *(float4*)&xL[row * 132 + kk] = v;
            }
            __syncthreads();
#pragma unroll
            for (int kk = 0; kk < 128; kk += 4) {
                float4 xv = *(const float4*)&xL[tt * 132 + kk];
                float4 wv = *(const float4*)&WgL[e * 1024 + kb + kk];
                acc += xv.x * wv.x + xv.y * wv.y + xv.z * wv.z + xv.w * wv.w;
            }
            __syncthreads();
        }

        float* lg = xL;
        lg[tt * 8 + e] = acc + bg[e];
        __syncthreads();
        if (t < 32) {
            float l[8];
#pragma unroll
            for (int i = 0; i < 8; ++i) l[i] = lg[t * 8 + i];
            float m = l[0];
#pragma unroll
            for (int i = 1; i < 8; ++i) m = fmaxf(m, l[i]);
            float s = 0.f;
#pragma unroll
            for (int i = 0; i < 8; ++i) { l[i] = __expf(l[i] - m); s += l[i]; }
            float inv = 1.0f / s;
            float4 p0 = make_float4(l[0]*inv, l[1]*inv, l[2]*inv, l[3]*inv);
            float4 p1 = make_float4(l[4]*inv, l[5]*inv, l[6]*inv, l[7]*inv);
            *(float4*)&g[(size_t)(n0 + tt) * 8]     = p0;
            *(float4*)&g[(size_t)(n0 + tt) * 8 + 4] = p1;
        }
    }
}

// ---------------------------------------------------------------------------
// Main MoE GEMM — expert-innermost restructure:
//  - A (tokens) shared across all 8 experts: per K-tile the A-frags are read
//    from LDS ONCE and reused for 8 expert B-panels -> 24 ds_read_b128 per
//    64 MFMA per wave (MFMA-bound ratio 2.67 vs R1's LDS-bound 0.67)
//  - acc[8][4] (128 regs) accumulates each expert over the FULL K; the
//    gate/bias merge runs exactly once in the epilogue -> no outAcc, no
//    global loads inside the K-loop (zero compiler-vmcnt interference)
//  - block: BM=256 x BN=32, 8 waves (4M x 2N), wave tile 64x16 per expert
//  - LDS: (A 256x64 + B 8x32x64) bf16 = 64KB x 2 buffers = 128KB, dbuf
//  - K-loop = 16 iters total; catalog minimum-2-phase: stage(t+1) at top,
//    compute tile t, vmcnt(0)+s_barrier at end (latency hides under body)
//  - LDS byte layout/swizzle identical to the measured conflict-free R2
//    scheme (128B rows, chunk ^ (row&7); linear cp16 dest, pre-swizzled src)
//  - XCD swizzle: bn XCD-local (B panels 2MB, L2-resident per XCD)
// ---------------------------------------------------------------------------
__global__ __launch_bounds__(512, 2) void moe_gemm_kernel(
    const unsigned short* __restrict__ xb,   // [NTOK][DIN] bf16
    const unsigned short* __restrict__ wt,   // [E][DOUT][DIN] bf16
    const float* __restrict__ g,             // [NTOK][E]
    const float* __restrict__ be,            // [E][DOUT]
    float* __restrict__ out)                 // [NTOK][DOUT]
{
    __shared__ unsigned short lA[2][256 * 64];   // 2 x 32 KB
    __shared__ unsigned short lB[2][256 * 64];   // 2 x 32 KB (8 experts x 32 cols)

    int bid = blockIdx.x;                 // 0..1023
    int xcd = bid & 7;
    int wl  = bid >> 3;                   // 0..127
    int bn  = xcd * 4 + (wl & 3);         // 0..31, XCD-local B panels
    int bm  = wl >> 2;                    // 0..31

    int tid  = threadIdx.x;               // 0..511
    int lane = tid & 63;
    int wave = tid >> 6;                  // 0..7
    int wm = wave >> 1;                   // 0..3 (64-row slab of 256)
    int wn = wave & 1;                    // 0..1 (16-col slab of 32)

    int rA   = lane & 15;
    int quad = lane >> 4;                 // k-subchunk 0..3
    int swz  = rA & 7;

    // staging geometry: thread covers (row = tid>>3 (+64*r), phys chunk tid&7);
    // phys chunk holds logical chunk (tid&7) ^ (row&7); cp16 dest is linear.
    int srow   = tid >> 3;                            // 0..63
    int schunk = ((tid & 7) ^ (srow & 7)) << 3;       // pre-swizzled src k-offset
    int wOff   = wave * 512;                          // elems; + r*4096

    const unsigned short* aP0 = xb + (size_t)(bm * 256 + srow) * DIN + schunk;
    const unsigned short* aP1 = aP0 + (size_t)64 * DIN;
    const unsigned short* aP2 = aP0 + (size_t)128 * DIN;
    const unsigned short* aP3 = aP0 + (size_t)192 * DIN;
    // B rounds r=0..3 cover rows r*64+srow of [e*32+col]; e = 2r + (srow>>5),
    // col = srow&31
    int eHi = srow >> 5;
    int col = srow & 31;
    const unsigned short* bP0 = wt + ((size_t)(0 + eHi) << 20) + (size_t)(bn * 32 + col) * DIN + schunk;
    const unsigned short* bP1 = wt + ((size_t)(2 + eHi) << 20) + (size_t)(bn * 32 + col) * DIN + schunk;
    const unsigned short* bP2 = wt + ((size_t)(4 + eHi) << 20) + (size_t)(bn * 32 + col) * DIN + schunk;
    const unsigned short* bP3 = wt + ((size_t)(6 + eHi) << 20) + (size_t)(bn * 32 + col) * DIN + schunk;

    // ---- prologue: stage K-tile 0 into buf0 ----
    cp16(aP0, &lA[0][0 * 4096 + wOff]);
    cp16(aP1, &lA[0][1 * 4096 + wOff]);
    cp16(aP2, &lA[0][2 * 4096 + wOff]);
    cp16(aP3, &lA[0][3 * 4096 + wOff]);
    cp16(bP0, &lB[0][0 * 4096 + wOff]);
    cp16(bP1, &lB[0][1 * 4096 + wOff]);
    cp16(bP2, &lB[0][2 * 4096 + wOff]);
    cp16(bP3, &lB[0][3 * 4096 + wOff]);

    f32x4 acc[8][4] = {};

    asm volatile("s_waitcnt vmcnt(0)" ::: "memory");
    BAR();

#pragma unroll 1
    for (int t = 0; t < 16; ++t) {
        // ---- issue stage of tile t+1 first (hides under this tile's MFMA) ----
        if (t < 15) {
            int nb = (t + 1) & 1;
            size_t ko = (size_t)(t + 1) * 64;
            cp16(aP0 + ko, &lA[nb][0 * 4096 + wOff]);
            cp16(aP1 + ko, &lA[nb][1 * 4096 + wOff]);
            cp16(aP2 + ko, &lA[nb][2 * 4096 + wOff]);
            cp16(aP3 + ko, &lA[nb][3 * 4096 + wOff]);
            cp16(bP0 + ko, &lB[nb][0 * 4096 + wOff]);
            cp16(bP1 + ko, &lB[nb][1 * 4096 + wOff]);
            cp16(bP2 + ko, &lB[nb][2 * 4096 + wOff]);
            cp16(bP3 + ko, &lB[nb][3 * 4096 + wOff]);
        }

        // ---- compute tile t: A-frags read once, reused for all 8 experts ----
        const unsigned short* A = lA[t & 1];
        const unsigned short* B = lB[t & 1];
#pragma unroll
        for (int h = 0; h < 2; ++h) {
            int kp = ((quad + h * 4) ^ swz) << 3;
            bf16x8 af[4];
#pragma unroll
            for (int i = 0; i < 4; ++i)
                af[i] = *(const bf16x8*)&A[(wm * 64 + i * 16 + rA) * 64 + kp];
            __builtin_amdgcn_s_setprio(1);
#pragma unroll
            for (int e = 0; e < 8; ++e) {
                bf16x8 bfr = *(const bf16x8*)&B[(e * 32 + wn * 16 + rA) * 64 + kp];
#pragma unroll
                for (int i = 0; i < 4; ++i)
                    acc[e][i] = __builtin_amdgcn_mfma_f32_16x16x32_bf16(
                        af[i], bfr, acc[e][i], 0, 0, 0);
            }
            __builtin_amdgcn_s_setprio(0);
        }

        // ---- end of iter: staged tile t+1 complete, swap ----
        if (t < 15) {
            asm volatile("s_waitcnt vmcnt(0)" ::: "memory");
            BAR();
        }
    }

    // ---- epilogue: out[n,col] = sum_e g[n,e] * (acc_e + be[e,col]) ----
    int colg = bn * 32 + wn * 16 + rA;
    float bcol[8];
#pragma unroll
    for (int e = 0; e < 8; ++e) bcol[e] = be[(size_t)e * DOUT + colg];
#pragma unroll
    for (int i = 0; i < 4; ++i) {
        int rbase = bm * 256 + wm * 64 + i * 16 + quad * 4;
#pragma unroll
        for (int rr = 0; rr < 4; ++rr) {
            const float* gp = &g[(size_t)(rbase + rr) * 8];
            float4 g0 = *(const float4*)gp;
            float4 g1 = *(const float4*)(gp + 4);
            float s = g0.x * (acc[0][i][rr] + bcol[0])
                    + g0.y * (acc[1][i][rr] + bcol[1])
                    + g0.z * (acc[2][i][rr] + bcol[2])
                    + g0.w * (acc[3][i][rr] + bcol[3])
                    + g1.x * (acc[4][i][rr] + bcol[4])
                    + g1.y * (acc[5][i][rr] + bcol[5])
                    + g1.z * (acc[6][i][rr] + bcol[6])
                    + g1.w * (acc[7][i][rr] + bcol[7]);
            out[(size_t)(rbase + rr) * DOUT + colg] = s;
        }
    }
}

// ---------------------------------------------------------------------------
extern "C" void kernel_launch(void* const* d_in, const int* in_sizes, int n_in,
                              void* d_out, int out_size, void* d_ws, size_t ws_size,
                              hipStream_t stream)
{
    const float* x  = (const float*)d_in[0];   // [8192,1024]
    const float* We = (const float*)d_in[1];   // [8,1024,1024]
    const float* be = (const float*)d_in[2];   // [8,1024]
    const float* Wg = (const float*)d_in[3];   // [1024,8]
    const float* bg = (const float*)d_in[4];   // [8]
    float* out = (float*)d_out;                // [8192,1024]

    // workspace: xb (16.78MB bf16) | WebT (16.78MB bf16) | g (256KB f32)
    unsigned short* xb = (unsigned short*)d_ws;
    unsigned short* wt = xb + (size_t)NTOK * DIN;
    float* g = (float*)(wt + (size_t)NEXP * DOUT * DIN);

    prep_kernel<<<2048 + 256, 256, 0, stream>>>(x, We, Wg, bg, xb, wt, g);
    moe_gemm_kernel<<<(NTOK / 256) * (DOUT / 32), 512, 0, stream>>>(xb, wt, g, be, out);
}

// Round 3
// 261.783 us; speedup vs baseline: 1.0973x; 1.0204x over previous
//
#include <hip/hip_runtime.h>
#include <hip/hip_bf16.h>
#include <cstdint>

// Problem constants
#define NTOK 8192
#define DIN  1024
#define DOUT 1024
#define NEXP 8

typedef __attribute__((ext_vector_type(8)))  __bf16 bf16x8;
typedef __attribute__((ext_vector_type(4)))  float  f32x4;

__device__ __forceinline__ unsigned short f2bf(float f) {
    unsigned int u = __builtin_bit_cast(unsigned int, f);
    u += 0x7FFFu + ((u >> 16) & 1u);   // round-to-nearest-even
    return (unsigned short)(u >> 16);
}

__device__ __forceinline__ void cp16(const void* gsrc, void* ldst) {
    __builtin_amdgcn_global_load_lds(
        (const __attribute__((address_space(1))) void*)gsrc,
        (__attribute__((address_space(3))) void*)ldst,
        16, 0, 0);
}

#define BAR() asm volatile("s_barrier" ::: "memory")

// ---------------------------------------------------------------------------
// Prep kernel (unchanged):
//   blocks [0, 2048):     We [e][k][o] fp32 -> WebT [e][o][k] bf16
//   blocks [2048, 2304):  gate softmax(x@Wg+bg) + x -> bf16
// ---------------------------------------------------------------------------
__global__ __launch_bounds__(256) void prep_kernel(
    const float* __restrict__ x, const float* __restrict__ We,
    const float* __restrict__ Wg, const float* __restrict__ bg,
    unsigned short* __restrict__ xb, unsigned short* __restrict__ wt,
    float* __restrict__ g)
{
    __shared__ float smem[12416];

    int t = threadIdx.x;

    if (blockIdx.x < 2048) {
        unsigned short* tile = (unsigned short*)smem;   // [64][72]
        int b = blockIdx.x;
        int e  = b >> 8;
        int kt = (b >> 4) & 15;
        int ot = b & 15;

        const float* src = We + ((size_t)e << 20) + (size_t)(kt * 64) * DOUT + ot * 64;
        unsigned short* dst = wt + ((size_t)e << 20) + (size_t)(ot * 64) * DIN + kt * 64;

        int kl = t >> 2;
        int og = (t & 3) * 16;
#pragma unroll
        for (int c = 0; c < 4; ++c) {
            int o = og + c * 4;
            float4 v = *(const float4*)&src[(size_t)kl * DOUT + o];
            ushort4 u;
            u.x = f2bf(v.x); u.y = f2bf(v.y); u.z = f2bf(v.z); u.w = f2bf(v.w);
            *(ushort4*)&tile[kl * 72 + o] = u;
        }
        __syncthreads();
        int ol = t >> 2;
        int kg = (t & 3) * 16;
        unsigned short tmp[16];
#pragma unroll
        for (int i = 0; i < 16; ++i) tmp[i] = tile[(kg + i) * 72 + ol];
        *(uint4*)&dst[(size_t)ol * DIN + kg]     = *(uint4*)&tmp[0];
        *(uint4*)&dst[(size_t)ol * DIN + kg + 8] = *(uint4*)&tmp[8];
    } else {
        float* WgL = smem;          // [8][1024] transposed Wg
        float* xL  = smem + 8192;   // [32][132] x chunk
        int n0 = (blockIdx.x - 2048) * 32;

#pragma unroll
        for (int q = 0; q < 8; ++q) {
            int fidx = q * 256 + t;
            int k  = fidx >> 1;
            int eh = (fidx & 1) * 4;
            float4 v = *(const float4*)&Wg[(size_t)k * 8 + eh];
            WgL[(eh + 0) * 1024 + k] = v.x;
            WgL[(eh + 1) * 1024 + k] = v.y;
            WgL[(eh + 2) * 1024 + k] = v.z;
            WgL[(eh + 3) * 1024 + k] = v.w;
        }

        int tt = t & 31;
        int e  = t >> 5;
        float acc = 0.f;

        for (int c = 0; c < 8; ++c) {
            int kb = c * 128;
#pragma unroll
            for (int q = 0; q < 4; ++q) {
                int fidx = q * 256 + t;
                int row = fidx >> 5;
                int kk  = (fidx & 31) * 4;
                float4 v = *(const float4*)&x[(size_t)(n0 + row) * DIN + kb + kk];
                ushort4 u;
                u.x = f2bf(v.x); u.y = f2bf(v.y); u.z = f2bf(v.z); u.w = f2bf(v.w);
                *(ushort4*)&xb[(size_t)(n0 + row) * DIN + kb + kk] = u;
                *(float4*)&xL[row * 132 + kk] = v;
            }
            __syncthreads();
#pragma unroll
            for (int kk = 0; kk < 128; kk += 4) {
                float4 xv = *(const float4*)&xL[tt * 132 + kk];
                float4 wv = *(const float4*)&WgL[e * 1024 + kb + kk];
                acc += xv.x * wv.x + xv.y * wv.y + xv.z * wv.z + xv.w * wv.w;
            }
            __syncthreads();
        }

        float* lg = xL;
        lg[tt * 8 + e] = acc + bg[e];
        __syncthreads();
        if (t < 32) {
            float l[8];
#pragma unroll
            for (int i = 0; i < 8; ++i) l[i] = lg[t * 8 + i];
            float m = l[0];
#pragma unroll
            for (int i = 1; i < 8; ++i) m = fmaxf(m, l[i]);
            float s = 0.f;
#pragma unroll
            for (int i = 0; i < 8; ++i) { l[i] = __expf(l[i] - m); s += l[i]; }
            float inv = 1.0f / s;
            float4 p0 = make_float4(l[0]*inv, l[1]*inv, l[2]*inv, l[3]*inv);
            float4 p1 = make_float4(l[4]*inv, l[5]*inv, l[6]*inv, l[7]*inv);
            *(float4*)&g[(size_t)(n0 + tt) * 8]     = p0;
            *(float4*)&g[(size_t)(n0 + tt) * 8 + 4] = p1;
        }
    }
}

// ---------------------------------------------------------------------------
// Main MoE GEMM — R2 geometry + m201-style 4-phase counted-vmcnt schedule:
//  - BM=256 x BN=32, E=8, BK=64, 8 waves (4Mx2N), dbuf LDS 128KB (as R2)
//  - per K-tile: 4 phases x 16 MFMA (expert pairs); A-frags read once in P0,
//    held in 32 VGPRs across phases (A amortized over all 8 experts)
//  - staging of tile t+1 spread 2 cp16/thread/phase (A halves at P0/P1 —
//    HBM-prone, issued 3-4 phases before their wait; B at P2/P3 — L2-hot)
//  - counted wait: P0 issues its 2 cp16 FIRST, then s_waitcnt vmcnt(2)
//    (tile t's 8 loads retired; 2 newest stay in flight). Drain-0 only at
//    the final tile. Per-phase s_barrier bounds skew to 1 phase; the
//    P3-end barrier is the dbuf-restage fence; P0's post-vmcnt barrier
//    publishes all waves' staged LDS writes.
//  - setprio(1) around each 16-MFMA cluster (T5)
//  - LDS byte layout / swizzle / staging geometry byte-identical to R2's
//    verified conflict-free scheme
// ---------------------------------------------------------------------------
__global__ __launch_bounds__(512, 2) void moe_gemm_kernel(
    const unsigned short* __restrict__ xb,   // [NTOK][DIN] bf16
    const unsigned short* __restrict__ wt,   // [E][DOUT][DIN] bf16
    const float* __restrict__ g,             // [NTOK][E]
    const float* __restrict__ be,            // [E][DOUT]
    float* __restrict__ out)                 // [NTOK][DOUT]
{
    __shared__ unsigned short lA[2][256 * 64];   // 2 x 32 KB
    __shared__ unsigned short lB[2][256 * 64];   // 2 x 32 KB (8e x 32col)

    int bid = blockIdx.x;                 // 0..1023
    int xcd = bid & 7;
    int wl  = bid >> 3;                   // 0..127
    int bn  = xcd * 4 + (wl & 3);         // 0..31, XCD-local B panels
    int bm  = wl >> 2;                    // 0..31

    int tid  = threadIdx.x;               // 0..511
    int lane = tid & 63;
    int wave = tid >> 6;                  // 0..7
    int wm = wave >> 1;                   // 0..3 (64-row slab of 256)
    int wn = wave & 1;                    // 0..1 (16-col slab of 32)

    int rA   = lane & 15;
    int quad = lane >> 4;                 // 0..3
    int swz  = rA & 7;
    int kp0  = (quad       ^ swz) << 3;   // k-half 0 chunk offset (elems)
    int kp1  = ((quad + 4) ^ swz) << 3;   // k-half 1

    // staging geometry (byte-identical to R2): thread covers
    // (row = base + tid>>3, phys chunk tid&7); phys holds logical ^ (row&7)
    int srow   = tid >> 3;                            // 0..63
    int schunk = ((tid & 7) ^ (srow & 7)) << 3;
    int wOff   = wave * 512;                          // elems

    const unsigned short* aBase = xb + (size_t)(bm * 256 + srow) * DIN + schunk;
    int eLo  = srow >> 5;                 // 0..1
    int colB = srow & 31;
    const unsigned short* bBase = wt + (size_t)(bn * 32 + colB) * DIN + schunk;

    // stage half H (rows [H*128, H*128+128)) of A/B for k-tile tt into buf b
#define STAGE_A(b, tt, H)                                                        \
    {   size_t ko = (size_t)(tt) * 64;                                           \
        cp16(aBase + (size_t)((H) * 128 +  0) * DIN + ko,                        \
             &lA[b][(H) * 8192 + 0 * 4096 + wOff]);                              \
        cp16(aBase + (size_t)((H) * 128 + 64) * DIN + ko,                        \
             &lA[b][(H) * 8192 + 1 * 4096 + wOff]); }
#define STAGE_B(b, tt, H)                                                        \
    {   size_t ko = (size_t)(tt) * 64;                                           \
        cp16(bBase + (((size_t)((H) * 4 + 0 + eLo)) << 20) + ko,                 \
             &lB[b][(H) * 8192 + 0 * 4096 + wOff]);                              \
        cp16(bBase + (((size_t)((H) * 4 + 2 + eLo)) << 20) + ko,                 \
             &lB[b][(H) * 8192 + 1 * 4096 + wOff]); }

    // ---- prologue: stage K-tile 0 into buf0 (8 loads in flight) ----
    STAGE_A(0, 0, 0); STAGE_A(0, 0, 1);
    STAGE_B(0, 0, 0); STAGE_B(0, 0, 1);

    f32x4 acc[8][4] = {};

#pragma unroll 1
    for (int t = 0; t < 16; ++t) {
        int c = t & 1, n = c ^ 1;
        const unsigned short* A = lA[c];
        const unsigned short* B = lB[c];

        // ================= P0: experts 0,1; stage A(t+1) half 0 =================
        if (t < 15) { STAGE_A(n, t + 1, 0);
                      asm volatile("s_waitcnt vmcnt(2)" ::: "memory"); }
        else        { asm volatile("s_waitcnt vmcnt(0)" ::: "memory"); }
        BAR();   // all waves' tile-t staging published

        bf16x8 af[4][2];
#pragma unroll
        for (int i = 0; i < 4; ++i) {
            af[i][0] = *(const bf16x8*)&A[(wm * 64 + i * 16 + rA) * 64 + kp0];
            af[i][1] = *(const bf16x8*)&A[(wm * 64 + i * 16 + rA) * 64 + kp1];
        }
        {
            bf16x8 b0h0 = *(const bf16x8*)&B[(0 * 32 + wn * 16 + rA) * 64 + kp0];
            bf16x8 b0h1 = *(const bf16x8*)&B[(0 * 32 + wn * 16 + rA) * 64 + kp1];
            bf16x8 b1h0 = *(const bf16x8*)&B[(1 * 32 + wn * 16 + rA) * 64 + kp0];
            bf16x8 b1h1 = *(const bf16x8*)&B[(1 * 32 + wn * 16 + rA) * 64 + kp1];
            __builtin_amdgcn_s_setprio(1);
#pragma unroll
            for (int i = 0; i < 4; ++i) {
                acc[0][i] = __builtin_amdgcn_mfma_f32_16x16x32_bf16(af[i][0], b0h0, acc[0][i], 0, 0, 0);
                acc[0][i] = __builtin_amdgcn_mfma_f32_16x16x32_bf16(af[i][1], b0h1, acc[0][i], 0, 0, 0);
                acc[1][i] = __builtin_amdgcn_mfma_f32_16x16x32_bf16(af[i][0], b1h0, acc[1][i], 0, 0, 0);
                acc[1][i] = __builtin_amdgcn_mfma_f32_16x16x32_bf16(af[i][1], b1h1, acc[1][i], 0, 0, 0);
            }
            __builtin_amdgcn_s_setprio(0);
        }
        BAR();

        // ================= P1: experts 2,3; stage A(t+1) half 1 =================
        if (t < 15) STAGE_A(n, t + 1, 1);
        {
            bf16x8 b0h0 = *(const bf16x8*)&B[(2 * 32 + wn * 16 + rA) * 64 + kp0];
            bf16x8 b0h1 = *(const bf16x8*)&B[(2 * 32 + wn * 16 + rA) * 64 + kp1];
            bf16x8 b1h0 = *(const bf16x8*)&B[(3 * 32 + wn * 16 + rA) * 64 + kp0];
            bf16x8 b1h1 = *(const bf16x8*)&B[(3 * 32 + wn * 16 + rA) * 64 + kp1];
            __builtin_amdgcn_s_setprio(1);
#pragma unroll
            for (int i = 0; i < 4; ++i) {
                acc[2][i] = __builtin_amdgcn_mfma_f32_16x16x32_bf16(af[i][0], b0h0, acc[2][i], 0, 0, 0);
                acc[2][i] = __builtin_amdgcn_mfma_f32_16x16x32_bf16(af[i][1], b0h1, acc[2][i], 0, 0, 0);
                acc[3][i] = __builtin_amdgcn_mfma_f32_16x16x32_bf16(af[i][0], b1h0, acc[3][i], 0, 0, 0);
                acc[3][i] = __builtin_amdgcn_mfma_f32_16x16x32_bf16(af[i][1], b1h1, acc[3][i], 0, 0, 0);
            }
            __builtin_amdgcn_s_setprio(0);
        }
        BAR();

        // ================= P2: experts 4,5; stage B(t+1) half 0 =================
        if (t < 15) STAGE_B(n, t + 1, 0);
        {
            bf16x8 b0h0 = *(const bf16x8*)&B[(4 * 32 + wn * 16 + rA) * 64 + kp0];
            bf16x8 b0h1 = *(const bf16x8*)&B[(4 * 32 + wn * 16 + rA) * 64 + kp1];
            bf16x8 b1h0 = *(const bf16x8*)&B[(5 * 32 + wn * 16 + rA) * 64 + kp0];
            bf16x8 b1h1 = *(const bf16x8*)&B[(5 * 32 + wn * 16 + rA) * 64 + kp1];
            __builtin_amdgcn_s_setprio(1);
#pragma unroll
            for (int i = 0; i < 4; ++i) {
                acc[4][i] = __builtin_amdgcn_mfma_f32_16x16x32_bf16(af[i][0], b0h0, acc[4][i], 0, 0, 0);
                acc[4][i] = __builtin_amdgcn_mfma_f32_16x16x32_bf16(af[i][1], b0h1, acc[4][i], 0, 0, 0);
                acc[5][i] = __builtin_amdgcn_mfma_f32_16x16x32_bf16(af[i][0], b1h0, acc[5][i], 0, 0, 0);
                acc[5][i] = __builtin_amdgcn_mfma_f32_16x16x32_bf16(af[i][1], b1h1, acc[5][i], 0, 0, 0);
            }
            __builtin_amdgcn_s_setprio(0);
        }
        BAR();

        // ================= P3: experts 6,7; stage B(t+1) half 1 =================
        if (t < 15) STAGE_B(n, t + 1, 1);
        {
            bf16x8 b0h0 = *(const bf16x8*)&B[(6 * 32 + wn * 16 + rA) * 64 + kp0];
            bf16x8 b0h1 = *(const bf16x8*)&B[(6 * 32 + wn * 16 + rA) * 64 + kp1];
            bf16x8 b1h0 = *(const bf16x8*)&B[(7 * 32 + wn * 16 + rA) * 64 + kp0];
            bf16x8 b1h1 = *(const bf16x8*)&B[(7 * 32 + wn * 16 + rA) * 64 + kp1];
            __builtin_amdgcn_s_setprio(1);
#pragma unroll
            for (int i = 0; i < 4; ++i) {
                acc[6][i] = __builtin_amdgcn_mfma_f32_16x16x32_bf16(af[i][0], b0h0, acc[6][i], 0, 0, 0);
                acc[6][i] = __builtin_amdgcn_mfma_f32_16x16x32_bf16(af[i][1], b0h1, acc[6][i], 0, 0, 0);
                acc[7][i] = __builtin_amdgcn_mfma_f32_16x16x32_bf16(af[i][0], b1h0, acc[7][i], 0, 0, 0);
                acc[7][i] = __builtin_amdgcn_mfma_f32_16x16x32_bf16(af[i][1], b1h1, acc[7][i], 0, 0, 0);
            }
            __builtin_amdgcn_s_setprio(0);
        }
        BAR();   // dbuf fence: all reads of buf c done before t+1 restages it
    }

    // ---- epilogue: out[n,col] = sum_e g[n,e] * (acc_e + be[e,col]) ----
    int colg = bn * 32 + wn * 16 + rA;
    float bcol[8];
#pragma unroll
    for (int e = 0; e < 8; ++e) bcol[e] = be[(size_t)e * DOUT + colg];
#pragma unroll
    for (int i = 0; i < 4; ++i) {
        int rbase = bm * 256 + wm * 64 + i * 16 + quad * 4;
#pragma unroll
        for (int rr = 0; rr < 4; ++rr) {
            const float* gp = &g[(size_t)(rbase + rr) * 8];
            float4 g0 = *(const float4*)gp;
            float4 g1 = *(const float4*)(gp + 4);
            float s = g0.x * (acc[0][i][rr] + bcol[0])
                    + g0.y * (acc[1][i][rr] + bcol[1])
                    + g0.z * (acc[2][i][rr] + bcol[2])
                    + g0.w * (acc[3][i][rr] + bcol[3])
                    + g1.x * (acc[4][i][rr] + bcol[4])
                    + g1.y * (acc[5][i][rr] + bcol[5])
                    + g1.z * (acc[6][i][rr] + bcol[6])
                    + g1.w * (acc[7][i][rr] + bcol[7]);
            out[(size_t)(rbase + rr) * DOUT + colg] = s;
        }
    }
}

// ---------------------------------------------------------------------------
extern "C" void kernel_launch(void* const* d_in, const int* in_sizes, int n_in,
                              void* d_out, int out_size, void* d_ws, size_t ws_size,
                              hipStream_t stream)
{
    const float* x  = (const float*)d_in[0];   // [8192,1024]
    const float* We = (const float*)d_in[1];   // [8,1024,1024]
    const float* be = (const float*)d_in[2];   // [8,1024]
    const float* Wg = (const float*)d_in[3];   // [1024,8]
    const float* bg = (const float*)d_in[4];   // [8]
    float* out = (float*)d_out;                // [8192,1024]

    // workspace: xb (16.78MB bf16) | WebT (16.78MB bf16) | g (256KB f32)
    unsigned short* xb = (unsigned short*)d_ws;
    unsigned short* wt = xb + (size_t)NTOK * DIN;
    float* g = (float*)(wt + (size_t)NEXP * DOUT * DIN);

    prep_kernel<<<2048 + 256, 256, 0, stream>>>(x, We, Wg, bg, xb, wt, g);
    moe_gemm_kernel<<<(NTOK / 256) * (DOUT / 32), 512, 0, stream>>>(xb, wt, g, be, out);
}